// Round 10
// baseline (75.558 us; speedup 1.0000x reference)
//
#include <hip/hip_runtime.h>
#include <hip/hip_fp16.h>

// DRN layer — economized-cubic / moment factorization, 8-byte LDS n-plane,
// software-pipelined weight loads. (R9 structure — best measured — + w prefetch.)
//
//  x = w*d2, |x| <= h = 0.1*(63/64)^2 = 0.0969.
//  exp(-x) ~= a0 - x + a2*x^2 - x^3/6   (Chebyshev-economized Taylor-4;
//      a2 = 1/2 + h^2/24, a0 = 1 - h^4/192; equioscillating err 4.6e-7)
//  Pw = a0*m0 * [1 + (-w)(N1 + (-w)(N2 + (-w)N3))]
//  a0*m0 is (j,l)-independent -> cancels in softmax.
//  M_n from raw moments mom_0..mom_6 via binomial in z = -s_l.
//  poly in [0.905,1.10] -> product over 64 k within 2^+-9.3: ONE log2 per j,
//  exp2-softmax safe with NO max-shift.
//
// grid = 512 (i = bid>>1, jh = bid&1) -> 2 blocks/CU; block = 512 = 8 waves;
// lane = l; wave owns 4 j. Main loop per (k,lane): ONE conflict-free ds_read_b64.
// Weight chunk k8+1 is prefetched (float4 pairs) before chunk k8's math so the
// global-load latency overlaps ~270 cyc of FMA work per chunk.

#define NUP 64
#define NLOW 64
#define QUP 64
#define QLOW 64

struct W8 { float4 a, b; };

__global__ __launch_bounds__(512, 4)
void drn_kernel(const float* __restrict__ P,
                const float* __restrict__ weight,
                const float* __restrict__ bias_abs,
                const float* __restrict__ bias_q,
                const float* __restrict__ lambda_abs,
                const float* __restrict__ lambda_q,
                float* __restrict__ out)
{
    __shared__ float  lds_mom[NLOW * 8];         // mom_0..mom_6 per k (+pad)  2 KB
    __shared__ float2 lds_n[NLOW * QUP];         // (n1 | n2,n3 fp16) per (k,l) 32 KB

    const int i    = blockIdx.x >> 1;
    const int jh   = blockIdx.x & 1;
    const int tid  = threadIdx.x;
    const int lane = tid & 63;
    const int wv   = __builtin_amdgcn_readfirstlane(tid >> 6);   // 0..7, uniform

    // ---------------- phase 1: raw moments mom_0..6 ----------------
    {
        const int kk = lane >> 3;
        const int mc = lane & 7;
        const int k  = wv * 8 + kk;
        const float* Pr = P + ((size_t)i * NLOW + k) * QLOW + mc * 8;
        const float4 pa = *reinterpret_cast<const float4*>(Pr);
        const float4 pb = *reinterpret_cast<const float4*>(Pr + 4);

        float t0 = 0.f, t1 = 0.f, t2 = 0.f, t3 = 0.f, t4 = 0.f, t5 = 0.f, t6 = 0.f;
        const float s0 = (float)(mc * 8) * 0.015625f;
#define ACCM(PV, S) { float f = (PV); const float s_ = (S); \
        t0 += f; f *= s_; t1 += f; f *= s_; t2 += f; f *= s_; t3 += f; \
        f *= s_; t4 += f; f *= s_; t5 += f; f *= s_; t6 += f; }
        ACCM(pa.x, s0);
        ACCM(pa.y, s0 + 0.015625f);
        ACCM(pa.z, s0 + 0.03125f);
        ACCM(pa.w, s0 + 0.046875f);
        ACCM(pb.x, s0 + 0.0625f);
        ACCM(pb.y, s0 + 0.078125f);
        ACCM(pb.z, s0 + 0.09375f);
        ACCM(pb.w, s0 + 0.109375f);
#undef ACCM
#define RED7(OFF) { t0 += __shfl_xor(t0, OFF, 64); t1 += __shfl_xor(t1, OFF, 64); \
        t2 += __shfl_xor(t2, OFF, 64); t3 += __shfl_xor(t3, OFF, 64); \
        t4 += __shfl_xor(t4, OFF, 64); t5 += __shfl_xor(t5, OFF, 64); \
        t6 += __shfl_xor(t6, OFF, 64); }
        RED7(1) RED7(2) RED7(4)
#undef RED7
        if (mc == 0) {
            float* mp = &lds_mom[k * 8];
            *reinterpret_cast<float4*>(mp)     = make_float4(t0, t1, t2, t3);
            *reinterpret_cast<float4*>(mp + 4) = make_float4(t4, t5, t6, 0.f);
        }
    }
    __syncthreads();

    // ---------------- phase 2: combine -> 8-byte n(k,l) plane ----------------
    const float s1l = (float)lane * 0.015625f;
    {
        const float A2 = 0.50039123f;            // 1/2 + h^2/24
        const float C6 = 1.0f / 6.0f;
        const float z  = -s1l;
        const float z2 = z * z, z3 = z2 * z, z4 = z2 * z2, z5 = z4 * z, z6 = z4 * z2;
        const float b10 = z2,        b11 = 2.f * z;
        const float b20 = z4,        b21 = 4.f * z3, b22 = 6.f * z2, b23 = 4.f * z;
        const float b30 = z6,        b31 = 6.f * z5, b32 = 15.f * z4,
                    b33 = 20.f * z3, b34 = 15.f * z2, b35 = 6.f * z;

#pragma unroll
        for (int kk = 0; kk < 8; ++kk) {
            const int k = wv * 8 + kk;
            const float4 q0 = *reinterpret_cast<const float4*>(&lds_mom[k * 8]);
            const float4 q1 = *reinterpret_cast<const float4*>(&lds_mom[k * 8 + 4]);

            const float inv = 1.0f / q0.x;       // 1/m0
            const float M1 = fmaf(b10, q0.x, fmaf(b11, q0.y, q0.z));
            const float M2 = fmaf(b20, q0.x, fmaf(b21, q0.y, fmaf(b22, q0.z,
                             fmaf(b23, q0.w, q1.x))));
            const float M3 = fmaf(b30, q0.x, fmaf(b31, q0.y, fmaf(b32, q0.z,
                             fmaf(b33, q0.w, fmaf(b34, q1.x, fmaf(b35, q1.y, q1.z))))));

            const float n1 = M1 * inv;
            const float n2 = A2 * M2 * inv;
            const float n3 = C6 * M3 * inv;

            union { __half2 h; float f; } pk;
            pk.h = __floats2half2_rn(n2, n3);
            float2 e; e.x = n1; e.y = pk.f;
            lds_n[k * QUP + lane] = e;
        }
    }
    __syncthreads();

    // ---------------- main loop: 64 k, this wave's 4 j's, w double-buffered ----------------
    const W8* __restrict__ w0q = reinterpret_cast<const W8*>(
        weight + (size_t)(jh * 32 + wv * 4 + 0) * NLOW);
    const W8* __restrict__ w1q = reinterpret_cast<const W8*>(
        weight + (size_t)(jh * 32 + wv * 4 + 1) * NLOW);
    const W8* __restrict__ w2q = reinterpret_cast<const W8*>(
        weight + (size_t)(jh * 32 + wv * 4 + 2) * NLOW);
    const W8* __restrict__ w3q = reinterpret_cast<const W8*>(
        weight + (size_t)(jh * 32 + wv * 4 + 3) * NLOW);

    W8 c0 = w0q[0], c1 = w1q[0], c2 = w2q[0], c3 = w3q[0];

    float pr0 = 1.f, pr1 = 1.f, pr2 = 1.f, pr3 = 1.f;
    for (int k8 = 0; k8 < 8; ++k8) {
        // prefetch next chunk before using the current one
        W8 nx0, nx1, nx2, nx3;
        if (k8 < 7) {
            nx0 = w0q[k8 + 1]; nx1 = w1q[k8 + 1];
            nx2 = w2q[k8 + 1]; nx3 = w3q[k8 + 1];
        }
        float w0[8], w1[8], w2[8], w3[8];
        __builtin_memcpy(w0, &c0, 32);
        __builtin_memcpy(w1, &c1, 32);
        __builtin_memcpy(w2, &c2, 32);
        __builtin_memcpy(w3, &c3, 32);

#pragma unroll
        for (int kk = 0; kk < 8; ++kk) {
            const float2 v = lds_n[(k8 * 8 + kk) * QUP + lane];
            union { float f; __half2 h; } pk; pk.f = v.y;
            const float2 n23 = __half22float2(pk.h);   // (n2, n3)
#define STEPJ(W, PR) { const float w_ = (W); \
            float t = fmaf(-w_, n23.y, n23.x); \
            t = fmaf(-w_, t, v.x); \
            PR *= fmaf(-w_, t, 1.0f); }
            STEPJ(w0[kk], pr0)
            STEPJ(w1[kk], pr1)
            STEPJ(w2[kk], pr2)
            STEPJ(w3[kk], pr3)
#undef STEPJ
        }
        if (k8 < 7) { c0 = nx0; c1 = nx1; c2 = nx2; c3 = nx3; }
    }

    // ---------------- epilogue: exponent_B + base-2 softmax (no max-shift) ----------------
    const float LOG2E = 1.4426950408889634f;
    auto finish = [&](float prv, int jj) {
        const int j = jh * 32 + wv * 4 + jj;
        const float dq = s1l - lambda_q[j];
        float y = __log2f(prv);                     // |y| <= ~9.3
        y = fmaf(-bias_q[j] * LOG2E, dq * dq, y);
        y = fmaf(-bias_abs[j] * LOG2E, fabsf(s1l - lambda_abs[j]), y);
        const float e = exp2f(y);                   // fp32-safe without max-shift
        float s = e;
#pragma unroll
        for (int off = 32; off >= 1; off >>= 1)
            s += __shfl_xor(s, off, 64);
        out[((size_t)i * NUP + j) * QUP + lane] = e / s;
    };
    finish(pr0, 0);
    finish(pr1, 1);
    finish(pr2, 2);
    finish(pr3, 3);
}

extern "C" void kernel_launch(void* const* d_in, const int* in_sizes, int n_in,
                              void* d_out, int out_size, void* d_ws, size_t ws_size,
                              hipStream_t stream) {
    const float* P          = (const float*)d_in[0];
    const float* weight     = (const float*)d_in[1];
    const float* bias_abs   = (const float*)d_in[2];
    const float* bias_q     = (const float*)d_in[3];
    const float* lambda_abs = (const float*)d_in[4];
    const float* lambda_q   = (const float*)d_in[5];
    (void)in_sizes; (void)n_in; (void)out_size; (void)d_ws; (void)ws_size;

    drn_kernel<<<dim3(512), dim3(512), 0, stream>>>(
        P, weight, bias_abs, bias_q, lambda_abs, lambda_q, (float*)d_out);
}